// Round 22
// baseline (138.446 us; speedup 1.0000x reference)
//
#include <hip/hip_runtime.h>
#include <hip/hip_bf16.h>
#include <cmath>

#define BATCH 32
#define H_IN 56
#define W_IN 56
#define N_IN (H_IN * W_IN)   // 3136
#define LKV 784              // 28*28 pooled kv length
#define LKV_PAD 864          // 27 tiles of 32
#define FRAG_ELEMS 82944     // per-batch K/V frag buffer elems (27*6*512)

typedef short bf16x8 __attribute__((ext_vector_type(8)));
typedef float f32x4 __attribute__((ext_vector_type(4)));
typedef float f32x16 __attribute__((ext_vector_type(16)));
typedef unsigned uintx2 __attribute__((ext_vector_type(2)));

__device__ __forceinline__ unsigned pack_bf16(float a, float b) {
    unsigned ua = __builtin_bit_cast(unsigned, a);
    unsigned ub = __builtin_bit_cast(unsigned, b);
    ua = (ua + 0x7FFFu + ((ua >> 16) & 1u)) >> 16;
    ub = (ub + 0x7FFFu + ((ub >> 16) & 1u)) >> 16;
    return ua | (ub << 16);
}

__device__ __forceinline__ unsigned short cvt_bf16(float a) {
    unsigned ua = __builtin_bit_cast(unsigned, a);
    return (unsigned short)((ua + 0x7FFFu + ((ua >> 16) & 1u)) >> 16);
}

__device__ __forceinline__ float bf16_to_f32(unsigned short u) {
    unsigned v = ((unsigned)u) << 16;
    return __builtin_bit_cast(float, v);
}

__device__ __forceinline__ float bflo(unsigned u) {
    return __builtin_bit_cast(float, u << 16);
}
__device__ __forceinline__ float bfhi(unsigned u) {
    return __builtin_bit_cast(float, u & 0xFFFF0000u);
}

// [lo16 = trunc-bf16(a), hi16 = trunc-bf16(b)] in one v_perm
__device__ __forceinline__ unsigned pack_trunc(float a, float b) {
    return __builtin_amdgcn_perm(__builtin_bit_cast(unsigned, b),
                                 __builtin_bit_cast(unsigned, a), 0x07060302u);
}

__device__ __forceinline__ f32x16 zero16() {
    f32x16 z;
#pragma unroll
    for (int i = 0; i < 16; ++i) z[i] = 0.f;
    return z;
}

// ---------------------------------------------------------------------------
// One-time W prep: both weights -> bf16 32x32 A-frag order.
//  idx < 3456: Wqkv fp32 [288][96] -> 54 frags (9 ct_out x 6 kb)
//  else      : Wproj fp32 [96][96] -> 18 frags (3 ct_out x 6 kb)
// frag(ct,kb): lane ln -> row = ct*32+(ln&31), k = kb*16+(ln>>5)*8 .. +7
// ---------------------------------------------------------------------------
__global__ __launch_bounds__(256) void wprep_kernel(
    const float* __restrict__ Wqkv, const float* __restrict__ Wproj,
    unsigned short* __restrict__ wq, unsigned short* __restrict__ wp32)
{
    int idx = blockIdx.x * 256 + threadIdx.x;   // 0..4607
    const float* src; unsigned short* dst; int li;
    if (idx < 3456) { src = Wqkv; dst = wq; li = idx; }
    else            { src = Wproj; dst = wp32; li = idx - 3456; }
    int frag = li >> 6, ln = li & 63;
    int ct = frag / 6, kb = frag % 6;
    int row = ct * 32 + (ln & 31);
    int k0 = kb * 16 + (ln >> 5) * 8;
    const float* s = src + row * 96 + k0;
    float4 v0 = *reinterpret_cast<const float4*>(s);
    float4 v1 = *reinterpret_cast<const float4*>(s + 4);
    uint4 o;
    o.x = pack_bf16(v0.x, v0.y); o.y = pack_bf16(v0.z, v0.w);
    o.z = pack_bf16(v1.x, v1.y); o.w = pack_bf16(v1.z, v1.w);
    *reinterpret_cast<uint4*>(dst + (size_t)li * 8) = o;
}

// ---------------------------------------------------------------------------
// MFMA GEMM v5: QKV projection on 32x32x16 MFMA, LDS-free.
// 256 thr / 4 waves; 32 tokens per wave (token = lane&31 is the D column).
// Per wave: 6 X B-frags (fp32->bf16), then 9 ct_out x {6 W-frag loads from
// L2, 6 MFMA, bias + bf16 store}. ~40% fewer instructions than the 16x16
// form for identical FLOPs. q = ct 0-2, k = 3-5, v = 6-8.
// ---------------------------------------------------------------------------
__global__ __launch_bounds__(256) void gemm5_kernel(
    const float* __restrict__ Xv, const unsigned short* __restrict__ Wfr,
    const float* __restrict__ bias, unsigned short* __restrict__ oq,
    unsigned short* __restrict__ ok, unsigned short* __restrict__ ov)
{
    const int tid = threadIdx.x;
    const int wid = tid >> 6, lane = tid & 63;
    const int l31 = lane & 31, h = lane >> 5;

    const size_t token = (size_t)blockIdx.x * 128 + wid * 32 + l31;
    bf16x8 xb[6];
#pragma unroll
    for (int kb = 0; kb < 6; ++kb) {
        const float* xp = Xv + token * 96 + kb * 16 + h * 8;
        float4 a = *reinterpret_cast<const float4*>(xp);
        float4 c = *reinterpret_cast<const float4*>(xp + 4);
        uint4 u;
        u.x = pack_bf16(a.x, a.y); u.y = pack_bf16(a.z, a.w);
        u.z = pack_bf16(c.x, c.y); u.w = pack_bf16(c.z, c.w);
        xb[kb] = __builtin_bit_cast(bf16x8, u);
    }

#pragma unroll
    for (int ct = 0; ct < 9; ++ct) {
        f32x16 acc = zero16();
#pragma unroll
        for (int kb = 0; kb < 6; ++kb) {
            bf16x8 wf = *reinterpret_cast<const bf16x8*>(
                Wfr + ((size_t)(ct * 6 + kb) * 64 + lane) * 8);
            acc = __builtin_amdgcn_mfma_f32_32x32x16_bf16(wf, xb[kb], acc, 0, 0, 0);
        }
        unsigned short* ob = (ct < 3) ? oq : (ct < 6 ? ok : ov);
        const int lbase = (ct % 3) * 32;
#pragma unroll
        for (int gblk = 0; gblk < 4; ++gblk) {
            int e = ct * 32 + gblk * 8 + 4 * h;
            float4 bv = *reinterpret_cast<const float4*>(bias + e);
            uint2 p;
            p.x = pack_bf16(acc[gblk * 4 + 0] + bv.x, acc[gblk * 4 + 1] + bv.y);
            p.y = pack_bf16(acc[gblk * 4 + 2] + bv.z, acc[gblk * 4 + 3] + bv.w);
            *reinterpret_cast<uint2*>(ob + token * 96 + lbase + gblk * 8 + 4 * h) = p;
        }
    }
}

// ---------------------------------------------------------------------------
// Fused pool kernel v5: all three conv+LN pools, 16 tokens/block (192 thr).
// Per-segment XCD swizzle (tap rows stay L2-resident). Conflict-free reduce.
// blocks [0,6272): q; [6272,8000): k (K-frag out, scaled); [8000,9728): v.
// ---------------------------------------------------------------------------
__global__ __launch_bounds__(192) void pool_all_kernel(
    const unsigned short* __restrict__ qin, const unsigned short* __restrict__ kin,
    const unsigned short* __restrict__ vin,
    const float* __restrict__ pqw, const float* __restrict__ pkw,
    const float* __restrict__ pvw,
    const float* __restrict__ gq, const float* __restrict__ betq,
    const float* __restrict__ gk, const float* __restrict__ betk,
    const float* __restrict__ gv, const float* __restrict__ betv,
    unsigned short* __restrict__ qout, unsigned short* __restrict__ kfr,
    unsigned short* __restrict__ vfr, float SC)
{
    __shared__ float wlds[864];
    __shared__ float2 part2[12][17];
    __shared__ float2 mrs[16];

    int blk0 = blockIdx.x;
    const unsigned short* in; const float* wsrc; const float* g; const float* beta;
    unsigned short* out; int omode, stride, Wp, LpPad; float oscale; int blk;
    if (blk0 < 6272) {
        blk = (blk0 & 7) * 784 + (blk0 >> 3);          // XCD swizzle (6272%8==0)
        in = qin; wsrc = pqw; g = gq; beta = betq; out = qout;
        omode = 0; stride = 1; Wp = 56; LpPad = N_IN; oscale = 1.0f;
    } else if (blk0 < 8000) {
        int r = blk0 - 6272;
        blk = (r & 7) * 216 + (r >> 3);                // 1728%8==0
        in = kin; wsrc = pkw; g = gk; beta = betk; out = kfr;
        omode = 1; stride = 2; Wp = 28; LpPad = LKV_PAD; oscale = SC;
    } else {
        int r = blk0 - 8000;
        blk = (r & 7) * 216 + (r >> 3);
        in = vin; wsrc = pvw; g = gv; beta = betv; out = vfr;
        omode = 2; stride = 2; Wp = 28; LpPad = LKV_PAD; oscale = 1.0f;
    }

    const int tid = threadIdx.x;
    for (int i = tid; i < 216; i += 192)
        *reinterpret_cast<float4*>(&wlds[i * 4]) =
            *reinterpret_cast<const float4*>(wsrc + i * 4);
    __syncthreads();

    const int tok_l = tid / 12, c8 = tid % 12;
    const int gt = blk * 16 + tok_l;
    const int Lp = (omode == 0) ? N_IN : LKV;
    const int b = gt / LpPad, rem = gt % LpPad;
    const bool pad = (rem >= Lp);
    const int yo = rem / Wp, xo = rem % Wp;

    float wt[9][8];
#pragma unroll
    for (int j = 0; j < 8; ++j) {
        const float* wr = &wlds[(c8 * 8 + j) * 9];
#pragma unroll
        for (int tap = 0; tap < 9; ++tap) wt[tap][j] = wr[tap];
    }

    float acc[8];
#pragma unroll
    for (int j = 0; j < 8; ++j) acc[j] = 0.f;

    const unsigned short* ib = in + (size_t)b * (H_IN * W_IN * 96) + c8 * 8;
#pragma unroll
    for (int dy = 0; dy < 3; ++dy) {
        const int iy = yo * stride + dy - 1;
        if ((unsigned)iy < (unsigned)H_IN) {
#pragma unroll
            for (int dx = 0; dx < 3; ++dx) {
                const int ix = xo * stride + dx - 1;
                if ((unsigned)ix < (unsigned)W_IN) {
                    const int tap = dy * 3 + dx;
                    uint4 d = *reinterpret_cast<const uint4*>(
                        ib + ((size_t)iy * W_IN + ix) * 96);
                    acc[0] += bflo(d.x) * wt[tap][0];
                    acc[1] += bfhi(d.x) * wt[tap][1];
                    acc[2] += bflo(d.y) * wt[tap][2];
                    acc[3] += bfhi(d.y) * wt[tap][3];
                    acc[4] += bflo(d.z) * wt[tap][4];
                    acc[5] += bfhi(d.z) * wt[tap][5];
                    acc[6] += bflo(d.w) * wt[tap][6];
                    acc[7] += bfhi(d.w) * wt[tap][7];
                }
            }
        }
    }

    float s = 0.f, s2 = 0.f;
#pragma unroll
    for (int j = 0; j < 8; ++j) { s += acc[j]; s2 += acc[j] * acc[j]; }
    part2[c8][tok_l] = make_float2(s, s2);
    __syncthreads();
    if (tid < 16) {
        float a = 0.f, q = 0.f;
#pragma unroll
        for (int j = 0; j < 12; ++j) {
            float2 p = part2[j][tid];
            a += p.x; q += p.y;
        }
        float mu = a * (1.f / 96.f);
        float var = q * (1.f / 96.f) - mu * mu;
        mrs[tid] = make_float2(mu, rsqrtf(var + 1e-6f));
    }
    __syncthreads();
    const float mu = mrs[tok_l].x, rstd = mrs[tok_l].y;

    float4 g0 = *reinterpret_cast<const float4*>(g + c8 * 8);
    float4 g1 = *reinterpret_cast<const float4*>(g + c8 * 8 + 4);
    float4 b0 = *reinterpret_cast<const float4*>(beta + c8 * 8);
    float4 b1 = *reinterpret_cast<const float4*>(beta + c8 * 8 + 4);
    float r[8];
    r[0] = (acc[0] - mu) * rstd * (g0.x * oscale) + b0.x * oscale;
    r[1] = (acc[1] - mu) * rstd * (g0.y * oscale) + b0.y * oscale;
    r[2] = (acc[2] - mu) * rstd * (g0.z * oscale) + b0.z * oscale;
    r[3] = (acc[3] - mu) * rstd * (g0.w * oscale) + b0.w * oscale;
    r[4] = (acc[4] - mu) * rstd * (g1.x * oscale) + b1.x * oscale;
    r[5] = (acc[5] - mu) * rstd * (g1.y * oscale) + b1.y * oscale;
    r[6] = (acc[6] - mu) * rstd * (g1.z * oscale) + b1.z * oscale;
    r[7] = (acc[7] - mu) * rstd * (g1.w * oscale) + b1.w * oscale;
    if (omode != 0 && pad) {
#pragma unroll
        for (int j = 0; j < 8; ++j) r[j] = 0.f;
    }

    if (omode == 0) {
        uint4 o;
        o.x = pack_bf16(r[0], r[1]); o.y = pack_bf16(r[2], r[3]);
        o.z = pack_bf16(r[4], r[5]); o.w = pack_bf16(r[6], r[7]);
        *reinterpret_cast<uint4*>(out + (size_t)gt * 96 + c8 * 8) = o;
    } else if (omode == 1) {
        int t = rem >> 5, kkb = c8 >> 1, hi = c8 & 1;
        int ln = (rem & 31) | (hi << 5);
        uint4 o;
        o.x = pack_bf16(r[0], r[1]); o.y = pack_bf16(r[2], r[3]);
        o.z = pack_bf16(r[4], r[5]); o.w = pack_bf16(r[6], r[7]);
        *reinterpret_cast<uint4*>(out + (size_t)b * FRAG_ELEMS +
                                  ((size_t)(t * 6 + kkb) * 64 + ln) * 8) = o;
    } else {
        int kv16 = rem >> 4, e = rem & 7, lh = (rem >> 3) & 1;
#pragma unroll
        for (int j = 0; j < 8; ++j) {
            int j8 = c8 * 8 + j;
            int ct = j8 >> 5;
            int ln = (j8 & 31) | (lh << 5);
            out[(size_t)b * FRAG_ELEMS + ((size_t)(kv16 * 3 + ct) * 64 + ln) * 8 + e] =
                cvt_bf16(r[j]);
        }
    }
}

// ---------------------------------------------------------------------------
// MFMA flash attention + residual + FUSED OUTPUT PROJECTION (fp32 out).
// R19 configuration (session best): proven v7/v11 loop body, permlane32_swap
// lane exchange (verified mapping; -24 VGPR vs ds_bpermute path).
// ---------------------------------------------------------------------------
#if __has_builtin(__builtin_amdgcn_permlane32_swap)
#define MAKE_BI(BI, D0, D1, D2, D3)                                           \
    int4 BI;                                                                  \
    {                                                                         \
        uintx2 rA_ = __builtin_amdgcn_permlane32_swap((D0), (D2), false, false); \
        uintx2 rB_ = __builtin_amdgcn_permlane32_swap((D1), (D3), false, false); \
        BI = make_int4((int)rA_[0], (int)rB_[0], (int)rA_[1], (int)rB_[1]);   \
    }
#else
#define MAKE_BI(BI, D0, D1, D2, D3)                                           \
    int4 BI;                                                                  \
    {                                                                         \
        unsigned s0_ = (unsigned)__shfl_xor((int)(D0), 32);                   \
        unsigned s1_ = (unsigned)__shfl_xor((int)(D1), 32);                   \
        unsigned s2_ = (unsigned)__shfl_xor((int)(D2), 32);                   \
        unsigned s3_ = (unsigned)__shfl_xor((int)(D3), 32);                   \
        BI = h ? make_int4((int)s2_, (int)s3_, (int)(D2), (int)(D3))          \
               : make_int4((int)(D0), (int)(D1), (int)s0_, (int)s1_);         \
    }
#endif

#define ATT_LOAD(KF, V0, V1, T)                                               \
    {                                                                         \
        _Pragma("unroll") for (int i_ = 0; i_ < 6; ++i_)                      \
            KF[i_] = *reinterpret_cast<const bf16x8*>(                        \
                Kb + ((size_t)((T) * 6 + i_) * 64 + lane) * 8);               \
        _Pragma("unroll") for (int c_ = 0; c_ < 3; ++c_) {                    \
            V0[c_] = *reinterpret_cast<const bf16x8*>(                        \
                Vb + ((size_t)((2 * (T)) * 3 + c_) * 64 + lane) * 8);         \
            V1[c_] = *reinterpret_cast<const bf16x8*>(                        \
                Vb + ((size_t)((2 * (T) + 1) * 3 + c_) * 64 + lane) * 8);     \
        }                                                                     \
    }

#define ATT_COMPUTE(KF, V0, V1, FULL)                                         \
    {                                                                         \
        f32x16 s = zero16();                                                  \
        _Pragma("unroll") for (int k_ = 0; k_ < 6; ++k_)                      \
            s = __builtin_amdgcn_mfma_f32_32x32x16_bf16(KF[k_], qf[k_], s, 0, 0, 0); \
        float p[16];                                                          \
        _Pragma("unroll") for (int r_ = 0; r_ < 16; ++r_)                     \
            p[r_] = __builtin_amdgcn_exp2f(s[r_]);                            \
        float q0_ = 0.f, q1_ = 0.f;                                           \
        _Pragma("unroll") for (int r_ = 0; r_ < 8; ++r_) {                    \
            q0_ += p[r_]; q1_ += p[r_ + 8];                                   \
        }                                                                     \
        lsum += q0_ + ((FULL) ? q1_ : 0.f);                                   \
        unsigned d[8];                                                        \
        _Pragma("unroll") for (int j_ = 0; j_ < 8; ++j_)                      \
            d[j_] = pack_trunc(p[2 * j_], p[2 * j_ + 1]);                     \
        {                                                                     \
            MAKE_BI(bi, d[0], d[1], d[2], d[3]);                              \
            bf16x8 bf = __builtin_bit_cast(bf16x8, bi);                       \
            a0 = __builtin_amdgcn_mfma_f32_32x32x16_bf16(V0[0], bf, a0, 0, 0, 0); \
            a1 = __builtin_amdgcn_mfma_f32_32x32x16_bf16(V0[1], bf, a1, 0, 0, 0); \
            a2 = __builtin_amdgcn_mfma_f32_32x32x16_bf16(V0[2], bf, a2, 0, 0, 0); \
        }                                                                     \
        if (FULL) {                                                           \
            MAKE_BI(bi, d[4], d[5], d[6], d[7]);                              \
            bf16x8 bf = __builtin_bit_cast(bf16x8, bi);                       \
            a0 = __builtin_amdgcn_mfma_f32_32x32x16_bf16(V1[0], bf, a0, 0, 0, 0); \
            a1 = __builtin_amdgcn_mfma_f32_32x32x16_bf16(V1[1], bf, a1, 0, 0, 0); \
            a2 = __builtin_amdgcn_mfma_f32_32x32x16_bf16(V1[2], bf, a2, 0, 0, 0); \
        }                                                                     \
    }

__global__ __launch_bounds__(64) void attn_proj_kernel(
    const unsigned short* __restrict__ qpl, const unsigned short* __restrict__ Kf,
    const unsigned short* __restrict__ Vf, const unsigned short* __restrict__ WP32,
    const float* __restrict__ bproj, float* __restrict__ outp)
{
    const int bid = blockIdx.x;                    // 0..3135
    const int swz = (bid & 7) * 392 + (bid >> 3);  // XCD grouping (3136%8==0)
    const int b = swz / 98, qblk = swz % 98;
    const int lane = threadIdx.x;
    const int l31 = lane & 31, h = lane >> 5;
    (void)h;

    const int qrow = qblk * 32 + l31;
    const unsigned short* qptr = qpl + ((size_t)b * N_IN + qrow) * 96;
    bf16x8 qf[6];
#pragma unroll
    for (int kkb = 0; kkb < 6; ++kkb)
        qf[kkb] = *reinterpret_cast<const bf16x8*>(qptr + kkb * 16 + h * 8);

    f32x16 a0 = zero16(), a1 = zero16(), a2 = zero16();
    float lsum = 0.f;

    const unsigned short* Kb = Kf + (size_t)b * FRAG_ELEMS;
    const unsigned short* Vb = Vf + (size_t)b * FRAG_ELEMS;

    bf16x8 kA[6], vA0[3], vA1[3];
    bf16x8 kB[6], vB0[3], vB1[3];

    ATT_LOAD(kA, vA0, vA1, 0);
    for (int t = 0; t < 24; t += 2) {
        ATT_LOAD(kB, vB0, vB1, t + 1);
        ATT_COMPUTE(kA, vA0, vA1, true);
        ATT_LOAD(kA, vA0, vA1, t + 2);
        ATT_COMPUTE(kB, vB0, vB1, true);
    }
    ATT_COMPUTE(kA, vA0, vA1, false);   // tile 24: kv-half 1 is all pad

    lsum += __shfl_xor(lsum, 32);
    const float inv = 1.f / lsum;

    // ---- fused epilogue: O' = acc*inv + q_res  -> bf16 words w[ct*8+m] ----
    unsigned w[24];
#pragma unroll
    for (int ct = 0; ct < 3; ++ct) {
        const f32x16& a = (ct == 0) ? a0 : (ct == 1 ? a1 : a2);
#pragma unroll
        for (int gblk = 0; gblk < 4; ++gblk) {
            int ch = ct * 32 + gblk * 8 + 4 * h;
            ushort4 q4 = *reinterpret_cast<const ushort4*>(qptr + ch);
            w[ct * 8 + 2 * gblk] =
                pack_bf16(a[gblk * 4 + 0] * inv + bf16_to_f32(q4.x),
                          a[gblk * 4 + 1] * inv + bf16_to_f32(q4.y));
            w[ct * 8 + 2 * gblk + 1] =
                pack_bf16(a[gblk * 4 + 2] * inv + bf16_to_f32(q4.z),
                          a[gblk * 4 + 3] * inv + bf16_to_f32(q4.w));
        }
    }

    // redistribute into proj B-frags: bfr[kb] holds k = kb*16 + h*8 + 0..7
    bf16x8 bfr[6];
#pragma unroll
    for (int kb = 0; kb < 6; ++kb) {
        const int base = (kb >> 1) * 8 + 4 * (kb & 1);
        MAKE_BI(bi, w[base], w[base + 1], w[base + 2], w[base + 3]);
        bfr[kb] = __builtin_bit_cast(bf16x8, bi);
    }

    // proj MFMA: out[e][q] = sum_ch Wproj[e][ch] * O'[ch][q]; + bias; store
    float* op = outp + ((size_t)b * N_IN + qrow) * 96;
#pragma unroll
    for (int ct = 0; ct < 3; ++ct) {
        f32x16 oa = zero16();
#pragma unroll
        for (int kb = 0; kb < 6; ++kb) {
            bf16x8 wf = *reinterpret_cast<const bf16x8*>(
                WP32 + ((size_t)(ct * 6 + kb) * 64 + lane) * 8);
            oa = __builtin_amdgcn_mfma_f32_32x32x16_bf16(wf, bfr[kb], oa, 0, 0, 0);
        }
#pragma unroll
        for (int gblk = 0; gblk < 4; ++gblk) {
            int e = ct * 32 + gblk * 8 + 4 * h;
            float4 bv = *reinterpret_cast<const float4*>(bproj + e);
            float4 o;
            o.x = oa[gblk * 4 + 0] + bv.x;
            o.y = oa[gblk * 4 + 1] + bv.y;
            o.z = oa[gblk * 4 + 2] + bv.z;
            o.w = oa[gblk * 4 + 3] + bv.w;
            *reinterpret_cast<float4*>(op + e) = o;
        }
    }
}

// ---------------------------------------------------------------------------
extern "C" void kernel_launch(void* const* d_in, const int* in_sizes, int n_in,
                              void* d_out, int out_size, void* d_ws, size_t ws_size,
                              hipStream_t stream)
{
    const float* x     = (const float*)d_in[0];
    const float* Wqkv  = (const float*)d_in[1];
    const float* bqkv  = (const float*)d_in[2];
    const float* pqw   = (const float*)d_in[3];
    const float* gq    = (const float*)d_in[4];
    const float* betq  = (const float*)d_in[5];
    const float* pkw   = (const float*)d_in[6];
    const float* gk    = (const float*)d_in[7];
    const float* betk  = (const float*)d_in[8];
    const float* pvw   = (const float*)d_in[9];
    const float* gv    = (const float*)d_in[10];
    const float* betv  = (const float*)d_in[11];
    const float* Wproj = (const float*)d_in[12];
    const float* bproj = (const float*)d_in[13];
    float* outp = (float*)d_out;

    char* ws = (char*)d_ws;
    const size_t QB    = (size_t)BATCH * N_IN * 96 * sizeof(short);       // 19.27 MB
    const size_t FRAGB = (size_t)BATCH * FRAG_ELEMS * sizeof(short);      // 5.31 MB
    unsigned short* qb   = (unsigned short*)(ws);
    unsigned short* kbuf = (unsigned short*)(ws + QB);
    unsigned short* vbuf = (unsigned short*)(ws + 2 * QB);
    unsigned short* qpb  = (unsigned short*)(ws + 3 * QB);
    unsigned short* Kfr  = (unsigned short*)(ws + 4 * QB);
    unsigned short* Vfr  = (unsigned short*)(ws + 4 * QB + FRAGB);
    unsigned short* wqf  = (unsigned short*)(ws + 4 * QB + 2 * FRAGB);
    unsigned short* wp32 = (unsigned short*)(ws + 4 * QB + 2 * FRAGB + 56320);

    const int T = BATCH * N_IN;      // 100352 = 128 * 784

    const float SC = 0.1020620726159658f * 1.4426950408889634f; // scale*log2e

    // 0. one-time W -> bf16 32x32 frag-order (Wqkv 54 frags; Wproj 18 frags)
    wprep_kernel<<<18, 256, 0, stream>>>(Wqkv, Wproj, wqf, wp32);
    // 1. QKV projection (32x32 MFMA, LDS-free) -> q,k,v bf16 [B][3136][96]
    gemm5_kernel<<<T / 128, 256, 0, stream>>>(
        x, wqf, bqkv, qb, kbuf, vbuf);
    // 2. fused pools v5 (conv+LN, XCD-swizzled, conflict-free reduce)
    pool_all_kernel<<<9728, 192, 0, stream>>>(
        qb, kbuf, vbuf, pqw, pkw, pvw, gq, betq, gk, betk, gv, betv,
        qpb, Kfr, Vfr, SC);
    // 3. attention + residual + fused output projection -> d_out (fp32)
    attn_proj_kernel<<<3136, 64, 0, stream>>>(
        qpb, Kfr, Vfr, wp32, bproj, outp);
}

// Round 23
// 127.308 us; speedup vs baseline: 1.0875x; 1.0875x over previous
//
#include <hip/hip_runtime.h>
#include <hip/hip_bf16.h>
#include <cmath>

#define BATCH 32
#define H_IN 56
#define W_IN 56
#define N_IN (H_IN * W_IN)   // 3136
#define LKV 784              // 28*28 pooled kv length
#define LKV_PAD 864          // 27 tiles of 32
#define FRAG_ELEMS 82944     // per-batch K/V frag buffer elems (27*6*512)

typedef short bf16x8 __attribute__((ext_vector_type(8)));
typedef float f32x4 __attribute__((ext_vector_type(4)));
typedef float f32x16 __attribute__((ext_vector_type(16)));
typedef unsigned uintx2 __attribute__((ext_vector_type(2)));

__device__ __forceinline__ unsigned pack_bf16(float a, float b) {
    unsigned ua = __builtin_bit_cast(unsigned, a);
    unsigned ub = __builtin_bit_cast(unsigned, b);
    ua = (ua + 0x7FFFu + ((ua >> 16) & 1u)) >> 16;
    ub = (ub + 0x7FFFu + ((ub >> 16) & 1u)) >> 16;
    return ua | (ub << 16);
}

__device__ __forceinline__ unsigned short cvt_bf16(float a) {
    unsigned ua = __builtin_bit_cast(unsigned, a);
    return (unsigned short)((ua + 0x7FFFu + ((ua >> 16) & 1u)) >> 16);
}

__device__ __forceinline__ float bf16_to_f32(unsigned short u) {
    unsigned v = ((unsigned)u) << 16;
    return __builtin_bit_cast(float, v);
}

__device__ __forceinline__ float bflo(unsigned u) {
    return __builtin_bit_cast(float, u << 16);
}
__device__ __forceinline__ float bfhi(unsigned u) {
    return __builtin_bit_cast(float, u & 0xFFFF0000u);
}

// [lo16 = trunc-bf16(a), hi16 = trunc-bf16(b)] in one v_perm
__device__ __forceinline__ unsigned pack_trunc(float a, float b) {
    return __builtin_amdgcn_perm(__builtin_bit_cast(unsigned, b),
                                 __builtin_bit_cast(unsigned, a), 0x07060302u);
}

__device__ __forceinline__ f32x16 zero16() {
    f32x16 z;
#pragma unroll
    for (int i = 0; i < 16; ++i) z[i] = 0.f;
    return z;
}

// ---------------------------------------------------------------------------
// One-time W prep:
//  idx < 3456: Wqkv fp32 [288][96] -> bf16 16x16 A-frag order (54 frags)
//  else      : Wproj fp32 [96][96] -> bf16 32x32 A-frag order (18 frags)
// ---------------------------------------------------------------------------
__global__ __launch_bounds__(256) void wprep_kernel(
    const float* __restrict__ Wqkv, const float* __restrict__ Wproj,
    unsigned short* __restrict__ wq, unsigned short* __restrict__ wp32)
{
    int idx = blockIdx.x * 256 + threadIdx.x;   // 0..4607
    if (idx < 3456) {
        int frag = idx >> 6, ln = idx & 63;
        int ct = frag / 3, kkb = frag % 3;
        int ch = ct * 16 + (ln & 15);
        int k0 = kkb * 32 + (ln >> 4) * 8;
        const float* s = Wqkv + ch * 96 + k0;
        float4 v0 = *reinterpret_cast<const float4*>(s);
        float4 v1 = *reinterpret_cast<const float4*>(s + 4);
        uint4 o;
        o.x = pack_bf16(v0.x, v0.y); o.y = pack_bf16(v0.z, v0.w);
        o.z = pack_bf16(v1.x, v1.y); o.w = pack_bf16(v1.z, v1.w);
        *reinterpret_cast<uint4*>(wq + (size_t)idx * 8) = o;
    } else {
        int li = idx - 3456;                 // 0..1151
        int frag = li >> 6, ln = li & 63;
        int ct_out = frag / 6, kb = frag % 6;
        int row = ct_out * 32 + (ln & 31);
        int k0 = kb * 16 + (ln >> 5) * 8;
        const float* s = Wproj + row * 96 + k0;
        float4 v0 = *reinterpret_cast<const float4*>(s);
        float4 v1 = *reinterpret_cast<const float4*>(s + 4);
        uint4 o;
        o.x = pack_bf16(v0.x, v0.y); o.y = pack_bf16(v0.z, v0.w);
        o.z = pack_bf16(v1.x, v1.y); o.w = pack_bf16(v1.z, v1.w);
        *reinterpret_cast<uint4*>(wp32 + (size_t)li * 8) = o;
    }
}

// ---------------------------------------------------------------------------
// MFMA GEMM v4: LDS-free. out[t][n] = sum_k X[t][k]*W[n][k] + bias[n]
// 256 thr / 4 waves; 128 tokens per block (32/wave = 2 iters x 16).
// (gemm5's 32x32 form regressed ~10 us: one-load-one-MFMA with a single
//  dependent chain loses to gemm4's 2x W-reuse + dual 16x16 chains.)
// ---------------------------------------------------------------------------
template <int NCT>
__global__ __launch_bounds__(256) void gemm4_kernel(
    const float* __restrict__ Xv, const unsigned short* __restrict__ Wfr,
    const float* __restrict__ bias, void* __restrict__ o0,
    void* __restrict__ o1, void* __restrict__ o2)
{
    const int tid = threadIdx.x;
    const int wid = tid >> 6, lane = tid & 63;
    const int lo16 = lane & 15, hi = lane >> 4;

    const size_t tok0 = (size_t)blockIdx.x * 128 + wid * 32;
    bf16x8 xb[6];
#pragma unroll
    for (int it = 0; it < 2; ++it) {
        size_t t = tok0 + it * 16 + lo16;
#pragma unroll
        for (int kkb = 0; kkb < 3; ++kkb) {
            const float* xp = Xv + t * 96 + kkb * 32 + hi * 8;
            float4 a = *reinterpret_cast<const float4*>(xp);
            float4 c = *reinterpret_cast<const float4*>(xp + 4);
            uint4 u;
            u.x = pack_bf16(a.x, a.y); u.y = pack_bf16(a.z, a.w);
            u.z = pack_bf16(c.x, c.y); u.w = pack_bf16(c.z, c.w);
            xb[it * 3 + kkb] = __builtin_bit_cast(bf16x8, u);
        }
    }

#pragma unroll
    for (int ct = 0; ct < NCT; ++ct) {
        bf16x8 wf[3];
#pragma unroll
        for (int kkb = 0; kkb < 3; ++kkb)
            wf[kkb] = *reinterpret_cast<const bf16x8*>(
                Wfr + ((size_t)(ct * 3 + kkb) * 64 + lane) * 8);
        const int chb = ct * 16 + hi * 4;
        float4 bv = *reinterpret_cast<const float4*>(bias + chb);
#pragma unroll
        for (int it = 0; it < 2; ++it) {
            f32x4 a = (f32x4){0.f, 0.f, 0.f, 0.f};
#pragma unroll
            for (int kkb = 0; kkb < 3; ++kkb)
                a = __builtin_amdgcn_mfma_f32_16x16x32_bf16(wf[kkb], xb[it * 3 + kkb], a, 0, 0, 0);
            size_t t = tok0 + it * 16 + lo16;
            float r0 = a[0] + bv.x, r1 = a[1] + bv.y;
            float r2 = a[2] + bv.z, r3 = a[3] + bv.w;
            unsigned short* ob =
                (unsigned short*)((ct < 6) ? o0 : (ct < 12 ? o1 : o2));
            int lch = (ct % 6) * 16 + hi * 4;
            uint2 p;
            p.x = pack_bf16(r0, r1);
            p.y = pack_bf16(r2, r3);
            *reinterpret_cast<uint2*>(ob + t * 96 + lch) = p;
        }
    }
}

// ---------------------------------------------------------------------------
// Fused pool kernel v5: all three conv+LN pools, 16 tokens/block (192 thr).
// Per-segment XCD swizzle (tap rows stay L2-resident). Conflict-free reduce.
// blocks [0,6272): q; [6272,8000): k (K-frag out, scaled); [8000,9728): v.
// ---------------------------------------------------------------------------
__global__ __launch_bounds__(192) void pool_all_kernel(
    const unsigned short* __restrict__ qin, const unsigned short* __restrict__ kin,
    const unsigned short* __restrict__ vin,
    const float* __restrict__ pqw, const float* __restrict__ pkw,
    const float* __restrict__ pvw,
    const float* __restrict__ gq, const float* __restrict__ betq,
    const float* __restrict__ gk, const float* __restrict__ betk,
    const float* __restrict__ gv, const float* __restrict__ betv,
    unsigned short* __restrict__ qout, unsigned short* __restrict__ kfr,
    unsigned short* __restrict__ vfr, float SC)
{
    __shared__ float wlds[864];
    __shared__ float2 part2[12][17];
    __shared__ float2 mrs[16];

    int blk0 = blockIdx.x;
    const unsigned short* in; const float* wsrc; const float* g; const float* beta;
    unsigned short* out; int omode, stride, Wp, LpPad; float oscale; int blk;
    if (blk0 < 6272) {
        blk = (blk0 & 7) * 784 + (blk0 >> 3);          // XCD swizzle (6272%8==0)
        in = qin; wsrc = pqw; g = gq; beta = betq; out = qout;
        omode = 0; stride = 1; Wp = 56; LpPad = N_IN; oscale = 1.0f;
    } else if (blk0 < 8000) {
        int r = blk0 - 6272;
        blk = (r & 7) * 216 + (r >> 3);                // 1728%8==0
        in = kin; wsrc = pkw; g = gk; beta = betk; out = kfr;
        omode = 1; stride = 2; Wp = 28; LpPad = LKV_PAD; oscale = SC;
    } else {
        int r = blk0 - 8000;
        blk = (r & 7) * 216 + (r >> 3);
        in = vin; wsrc = pvw; g = gv; beta = betv; out = vfr;
        omode = 2; stride = 2; Wp = 28; LpPad = LKV_PAD; oscale = 1.0f;
    }

    const int tid = threadIdx.x;
    for (int i = tid; i < 216; i += 192)
        *reinterpret_cast<float4*>(&wlds[i * 4]) =
            *reinterpret_cast<const float4*>(wsrc + i * 4);
    __syncthreads();

    const int tok_l = tid / 12, c8 = tid % 12;
    const int gt = blk * 16 + tok_l;
    const int Lp = (omode == 0) ? N_IN : LKV;
    const int b = gt / LpPad, rem = gt % LpPad;
    const bool pad = (rem >= Lp);
    const int yo = rem / Wp, xo = rem % Wp;

    float wt[9][8];
#pragma unroll
    for (int j = 0; j < 8; ++j) {
        const float* wr = &wlds[(c8 * 8 + j) * 9];
#pragma unroll
        for (int tap = 0; tap < 9; ++tap) wt[tap][j] = wr[tap];
    }

    float acc[8];
#pragma unroll
    for (int j = 0; j < 8; ++j) acc[j] = 0.f;

    const unsigned short* ib = in + (size_t)b * (H_IN * W_IN * 96) + c8 * 8;
#pragma unroll
    for (int dy = 0; dy < 3; ++dy) {
        const int iy = yo * stride + dy - 1;
        if ((unsigned)iy < (unsigned)H_IN) {
#pragma unroll
            for (int dx = 0; dx < 3; ++dx) {
                const int ix = xo * stride + dx - 1;
                if ((unsigned)ix < (unsigned)W_IN) {
                    const int tap = dy * 3 + dx;
                    uint4 d = *reinterpret_cast<const uint4*>(
                        ib + ((size_t)iy * W_IN + ix) * 96);
                    acc[0] += bflo(d.x) * wt[tap][0];
                    acc[1] += bfhi(d.x) * wt[tap][1];
                    acc[2] += bflo(d.y) * wt[tap][2];
                    acc[3] += bfhi(d.y) * wt[tap][3];
                    acc[4] += bflo(d.z) * wt[tap][4];
                    acc[5] += bfhi(d.z) * wt[tap][5];
                    acc[6] += bflo(d.w) * wt[tap][6];
                    acc[7] += bfhi(d.w) * wt[tap][7];
                }
            }
        }
    }

    float s = 0.f, s2 = 0.f;
#pragma unroll
    for (int j = 0; j < 8; ++j) { s += acc[j]; s2 += acc[j] * acc[j]; }
    part2[c8][tok_l] = make_float2(s, s2);
    __syncthreads();
    if (tid < 16) {
        float a = 0.f, q = 0.f;
#pragma unroll
        for (int j = 0; j < 12; ++j) {
            float2 p = part2[j][tid];
            a += p.x; q += p.y;
        }
        float mu = a * (1.f / 96.f);
        float var = q * (1.f / 96.f) - mu * mu;
        mrs[tid] = make_float2(mu, rsqrtf(var + 1e-6f));
    }
    __syncthreads();
    const float mu = mrs[tok_l].x, rstd = mrs[tok_l].y;

    float4 g0 = *reinterpret_cast<const float4*>(g + c8 * 8);
    float4 g1 = *reinterpret_cast<const float4*>(g + c8 * 8 + 4);
    float4 b0 = *reinterpret_cast<const float4*>(beta + c8 * 8);
    float4 b1 = *reinterpret_cast<const float4*>(beta + c8 * 8 + 4);
    float r[8];
    r[0] = (acc[0] - mu) * rstd * (g0.x * oscale) + b0.x * oscale;
    r[1] = (acc[1] - mu) * rstd * (g0.y * oscale) + b0.y * oscale;
    r[2] = (acc[2] - mu) * rstd * (g0.z * oscale) + b0.z * oscale;
    r[3] = (acc[3] - mu) * rstd * (g0.w * oscale) + b0.w * oscale;
    r[4] = (acc[4] - mu) * rstd * (g1.x * oscale) + b1.x * oscale;
    r[5] = (acc[5] - mu) * rstd * (g1.y * oscale) + b1.y * oscale;
    r[6] = (acc[6] - mu) * rstd * (g1.z * oscale) + b1.z * oscale;
    r[7] = (acc[7] - mu) * rstd * (g1.w * oscale) + b1.w * oscale;
    if (omode != 0 && pad) {
#pragma unroll
        for (int j = 0; j < 8; ++j) r[j] = 0.f;
    }

    if (omode == 0) {
        uint4 o;
        o.x = pack_bf16(r[0], r[1]); o.y = pack_bf16(r[2], r[3]);
        o.z = pack_bf16(r[4], r[5]); o.w = pack_bf16(r[6], r[7]);
        *reinterpret_cast<uint4*>(out + (size_t)gt * 96 + c8 * 8) = o;
    } else if (omode == 1) {
        int t = rem >> 5, kkb = c8 >> 1, hi = c8 & 1;
        int ln = (rem & 31) | (hi << 5);
        uint4 o;
        o.x = pack_bf16(r[0], r[1]); o.y = pack_bf16(r[2], r[3]);
        o.z = pack_bf16(r[4], r[5]); o.w = pack_bf16(r[6], r[7]);
        *reinterpret_cast<uint4*>(out + (size_t)b * FRAG_ELEMS +
                                  ((size_t)(t * 6 + kkb) * 64 + ln) * 8) = o;
    } else {
        int kv16 = rem >> 4, e = rem & 7, lh = (rem >> 3) & 1;
#pragma unroll
        for (int j = 0; j < 8; ++j) {
            int j8 = c8 * 8 + j;
            int ct = j8 >> 5;
            int ln = (j8 & 31) | (lh << 5);
            out[(size_t)b * FRAG_ELEMS + ((size_t)(kv16 * 3 + ct) * 64 + ln) * 8 + e] =
                cvt_bf16(r[j]);
        }
    }
}

// ---------------------------------------------------------------------------
// MFMA flash attention + residual + FUSED OUTPUT PROJECTION (fp32 out).
// R19/R21 configuration (session best, verified twice): proven v7/v11 loop
// body, permlane32_swap lane exchange (verified mapping; -24 VGPR).
// ---------------------------------------------------------------------------
#if __has_builtin(__builtin_amdgcn_permlane32_swap)
#define MAKE_BI(BI, D0, D1, D2, D3)                                           \
    int4 BI;                                                                  \
    {                                                                         \
        uintx2 rA_ = __builtin_amdgcn_permlane32_swap((D0), (D2), false, false); \
        uintx2 rB_ = __builtin_amdgcn_permlane32_swap((D1), (D3), false, false); \
        BI = make_int4((int)rA_[0], (int)rB_[0], (int)rA_[1], (int)rB_[1]);   \
    }
#else
#define MAKE_BI(BI, D0, D1, D2, D3)                                           \
    int4 BI;                                                                  \
    {                                                                         \
        unsigned s0_ = (unsigned)__shfl_xor((int)(D0), 32);                   \
        unsigned s1_ = (unsigned)__shfl_xor((int)(D1), 32);                   \
        unsigned s2_ = (unsigned)__shfl_xor((int)(D2), 32);                   \
        unsigned s3_ = (unsigned)__shfl_xor((int)(D3), 32);                   \
        BI = h ? make_int4((int)s2_, (int)s3_, (int)(D2), (int)(D3))          \
               : make_int4((int)(D0), (int)(D1), (int)s0_, (int)s1_);         \
    }
#endif

#define ATT_LOAD(KF, V0, V1, T)                                               \
    {                                                                         \
        _Pragma("unroll") for (int i_ = 0; i_ < 6; ++i_)                      \
            KF[i_] = *reinterpret_cast<const bf16x8*>(                        \
                Kb + ((size_t)((T) * 6 + i_) * 64 + lane) * 8);               \
        _Pragma("unroll") for (int c_ = 0; c_ < 3; ++c_) {                    \
            V0[c_] = *reinterpret_cast<const bf16x8*>(                        \
                Vb + ((size_t)((2 * (T)) * 3 + c_) * 64 + lane) * 8);         \
            V1[c_] = *reinterpret_cast<const bf16x8*>(                        \
                Vb + ((size_t)((2 * (T) + 1) * 3 + c_) * 64 + lane) * 8);     \
        }                                                                     \
    }

#define ATT_COMPUTE(KF, V0, V1, FULL)                                         \
    {                                                                         \
        f32x16 s = zero16();                                                  \
        _Pragma("unroll") for (int k_ = 0; k_ < 6; ++k_)                      \
            s = __builtin_amdgcn_mfma_f32_32x32x16_bf16(KF[k_], qf[k_], s, 0, 0, 0); \
        float p[16];                                                          \
        _Pragma("unroll") for (int r_ = 0; r_ < 16; ++r_)                     \
            p[r_] = __builtin_amdgcn_exp2f(s[r_]);                            \
        float q0_ = 0.f, q1_ = 0.f;                                           \
        _Pragma("unroll") for (int r_ = 0; r_ < 8; ++r_) {                    \
            q0_ += p[r_]; q1_ += p[r_ + 8];                                   \
        }                                                                     \
        lsum += q0_ + ((FULL) ? q1_ : 0.f);                                   \
        unsigned d[8];                                                        \
        _Pragma("unroll") for (int j_ = 0; j_ < 8; ++j_)                      \
            d[j_] = pack_trunc(p[2 * j_], p[2 * j_ + 1]);                     \
        {                                                                     \
            MAKE_BI(bi, d[0], d[1], d[2], d[3]);                              \
            bf16x8 bf = __builtin_bit_cast(bf16x8, bi);                       \
            a0 = __builtin_amdgcn_mfma_f32_32x32x16_bf16(V0[0], bf, a0, 0, 0, 0); \
            a1 = __builtin_amdgcn_mfma_f32_32x32x16_bf16(V0[1], bf, a1, 0, 0, 0); \
            a2 = __builtin_amdgcn_mfma_f32_32x32x16_bf16(V0[2], bf, a2, 0, 0, 0); \
        }                                                                     \
        if (FULL) {                                                           \
            MAKE_BI(bi, d[4], d[5], d[6], d[7]);                              \
            bf16x8 bf = __builtin_bit_cast(bf16x8, bi);                       \
            a0 = __builtin_amdgcn_mfma_f32_32x32x16_bf16(V1[0], bf, a0, 0, 0, 0); \
            a1 = __builtin_amdgcn_mfma_f32_32x32x16_bf16(V1[1], bf, a1, 0, 0, 0); \
            a2 = __builtin_amdgcn_mfma_f32_32x32x16_bf16(V1[2], bf, a2, 0, 0, 0); \
        }                                                                     \
    }

__global__ __launch_bounds__(64) void attn_proj_kernel(
    const unsigned short* __restrict__ qpl, const unsigned short* __restrict__ Kf,
    const unsigned short* __restrict__ Vf, const unsigned short* __restrict__ WP32,
    const float* __restrict__ bproj, float* __restrict__ outp)
{
    const int bid = blockIdx.x;                    // 0..3135
    const int swz = (bid & 7) * 392 + (bid >> 3);  // XCD grouping (3136%8==0)
    const int b = swz / 98, qblk = swz % 98;
    const int lane = threadIdx.x;
    const int l31 = lane & 31, h = lane >> 5;
    (void)h;

    const int qrow = qblk * 32 + l31;
    const unsigned short* qptr = qpl + ((size_t)b * N_IN + qrow) * 96;
    bf16x8 qf[6];
#pragma unroll
    for (int kkb = 0; kkb < 6; ++kkb)
        qf[kkb] = *reinterpret_cast<const bf16x8*>(qptr + kkb * 16 + h * 8);

    f32x16 a0 = zero16(), a1 = zero16(), a2 = zero16();
    float lsum = 0.f;

    const unsigned short* Kb = Kf + (size_t)b * FRAG_ELEMS;
    const unsigned short* Vb = Vf + (size_t)b * FRAG_ELEMS;

    bf16x8 kA[6], vA0[3], vA1[3];
    bf16x8 kB[6], vB0[3], vB1[3];

    ATT_LOAD(kA, vA0, vA1, 0);
    for (int t = 0; t < 24; t += 2) {
        ATT_LOAD(kB, vB0, vB1, t + 1);
        ATT_COMPUTE(kA, vA0, vA1, true);
        ATT_LOAD(kA, vA0, vA1, t + 2);
        ATT_COMPUTE(kB, vB0, vB1, true);
    }
    ATT_COMPUTE(kA, vA0, vA1, false);   // tile 24: kv-half 1 is all pad

    lsum += __shfl_xor(lsum, 32);
    const float inv = 1.f / lsum;

    // ---- fused epilogue: O' = acc*inv + q_res  -> bf16 words w[ct*8+m] ----
    unsigned w[24];
#pragma unroll
    for (int ct = 0; ct < 3; ++ct) {
        const f32x16& a = (ct == 0) ? a0 : (ct == 1 ? a1 : a2);
#pragma unroll
        for (int gblk = 0; gblk < 4; ++gblk) {
            int ch = ct * 32 + gblk * 8 + 4 * h;
            ushort4 q4 = *reinterpret_cast<const ushort4*>(qptr + ch);
            w[ct * 8 + 2 * gblk] =
                pack_bf16(a[gblk * 4 + 0] * inv + bf16_to_f32(q4.x),
                          a[gblk * 4 + 1] * inv + bf16_to_f32(q4.y));
            w[ct * 8 + 2 * gblk + 1] =
                pack_bf16(a[gblk * 4 + 2] * inv + bf16_to_f32(q4.z),
                          a[gblk * 4 + 3] * inv + bf16_to_f32(q4.w));
        }
    }

    // redistribute into proj B-frags: bfr[kb] holds k = kb*16 + h*8 + 0..7
    bf16x8 bfr[6];
#pragma unroll
    for (int kb = 0; kb < 6; ++kb) {
        const int base = (kb >> 1) * 8 + 4 * (kb & 1);
        MAKE_BI(bi, w[base], w[base + 1], w[base + 2], w[base + 3]);
        bfr[kb] = __builtin_bit_cast(bf16x8, bi);
    }

    // proj MFMA: out[e][q] = sum_ch Wproj[e][ch] * O'[ch][q]; + bias; store
    float* op = outp + ((size_t)b * N_IN + qrow) * 96;
#pragma unroll
    for (int ct = 0; ct < 3; ++ct) {
        f32x16 oa = zero16();
#pragma unroll
        for (int kb = 0; kb < 6; ++kb) {
            bf16x8 wf = *reinterpret_cast<const bf16x8*>(
                WP32 + ((size_t)(ct * 6 + kb) * 64 + lane) * 8);
            oa = __builtin_amdgcn_mfma_f32_32x32x16_bf16(wf, bfr[kb], oa, 0, 0, 0);
        }
#pragma unroll
        for (int gblk = 0; gblk < 4; ++gblk) {
            int e = ct * 32 + gblk * 8 + 4 * h;
            float4 bv = *reinterpret_cast<const float4*>(bproj + e);
            float4 o;
            o.x = oa[gblk * 4 + 0] + bv.x;
            o.y = oa[gblk * 4 + 1] + bv.y;
            o.z = oa[gblk * 4 + 2] + bv.z;
            o.w = oa[gblk * 4 + 3] + bv.w;
            *reinterpret_cast<float4*>(op + e) = o;
        }
    }
}

// ---------------------------------------------------------------------------
extern "C" void kernel_launch(void* const* d_in, const int* in_sizes, int n_in,
                              void* d_out, int out_size, void* d_ws, size_t ws_size,
                              hipStream_t stream)
{
    const float* x     = (const float*)d_in[0];
    const float* Wqkv  = (const float*)d_in[1];
    const float* bqkv  = (const float*)d_in[2];
    const float* pqw   = (const float*)d_in[3];
    const float* gq    = (const float*)d_in[4];
    const float* betq  = (const float*)d_in[5];
    const float* pkw   = (const float*)d_in[6];
    const float* gk    = (const float*)d_in[7];
    const float* betk  = (const float*)d_in[8];
    const float* pvw   = (const float*)d_in[9];
    const float* gv    = (const float*)d_in[10];
    const float* betv  = (const float*)d_in[11];
    const float* Wproj = (const float*)d_in[12];
    const float* bproj = (const float*)d_in[13];
    float* outp = (float*)d_out;

    char* ws = (char*)d_ws;
    const size_t QB    = (size_t)BATCH * N_IN * 96 * sizeof(short);       // 19.27 MB
    const size_t FRAGB = (size_t)BATCH * FRAG_ELEMS * sizeof(short);      // 5.31 MB
    unsigned short* qb   = (unsigned short*)(ws);
    unsigned short* kbuf = (unsigned short*)(ws + QB);
    unsigned short* vbuf = (unsigned short*)(ws + 2 * QB);
    unsigned short* qpb  = (unsigned short*)(ws + 3 * QB);
    unsigned short* Kfr  = (unsigned short*)(ws + 4 * QB);
    unsigned short* Vfr  = (unsigned short*)(ws + 4 * QB + FRAGB);
    unsigned short* wqf  = (unsigned short*)(ws + 4 * QB + 2 * FRAGB);
    unsigned short* wp32 = (unsigned short*)(ws + 4 * QB + 2 * FRAGB + 56320);

    const int T = BATCH * N_IN;      // 100352 = 128 * 784

    const float SC = 0.1020620726159658f * 1.4426950408889634f; // scale*log2e

    // 0. one-time W -> bf16 frag-order (Wqkv 16x16; Wproj 32x32 for fusion)
    wprep_kernel<<<18, 256, 0, stream>>>(Wqkv, Wproj, wqf, wp32);
    // 1. QKV projection (MFMA, LDS-free) -> q,k,v bf16 [B][3136][96]
    gemm4_kernel<18><<<T / 128, 256, 0, stream>>>(
        x, wqf, bqkv, qb, kbuf, vbuf);
    // 2. fused pools v5 (conv+LN, XCD-swizzled, conflict-free reduce)
    pool_all_kernel<<<9728, 192, 0, stream>>>(
        qb, kbuf, vbuf, pqw, pkw, pvw, gq, betq, gk, betk, gv, betv,
        qpb, Kfr, Vfr, SC);
    // 3. attention + residual + fused output projection -> d_out (fp32)
    attn_proj_kernel<<<3136, 64, 0, stream>>>(
        qpb, Kfr, Vfr, wp32, bproj, outp);
}